// Round 1
// baseline (89.440 us; speedup 1.0000x reference)
//
#include <hip/hip_runtime.h>

#define NQ 4
#define DIM 16
#define NL 3

// Precompute cos/sin of weights/2 (12 uniform gates) into workspace.
__global__ void qlayer_prep(const float* __restrict__ w, float* __restrict__ ws) {
    int i = threadIdx.x;
    if (i < NL * NQ) {
        float t = 0.5f * w[i];
        ws[i]           = cosf(t);
        ws[i + NL * NQ] = sinf(t);
    }
}

__global__ __launch_bounds__(256) void qlayer_main(const float* __restrict__ inputs,
                                                   const float* __restrict__ wcs,
                                                   float* __restrict__ out, int B) {
    int b = blockIdx.x * blockDim.x + threadIdx.x;
    if (b >= B) return;

    // Uniform weight cos/sin (scalar loads, L2-resident).
    float cw[NL * NQ], sw[NL * NQ];
#pragma unroll
    for (int i = 0; i < NL * NQ; ++i) {
        cw[i] = wcs[i];
        sw[i] = wcs[i + NL * NQ];
    }

    // Per-batch RY angles (vectorized 16B load).
    float4 in = reinterpret_cast<const float4*>(inputs)[b];
    float ci[NQ], si[NQ];
    {
        float a;
        a = 0.5f * in.x; ci[0] = __cosf(a); si[0] = __sinf(a);
        a = 0.5f * in.y; ci[1] = __cosf(a); si[1] = __sinf(a);
        a = 0.5f * in.z; ci[2] = __cosf(a); si[2] = __sinf(a);
        a = 0.5f * in.w; ci[3] = __cosf(a); si[3] = __sinf(a);
    }

    // Initial state after the batched RY layer: product state, all-real.
    // Qubit q corresponds to bit (3-q) of the state index (MSB-first).
    float re[DIM], im[DIM];
#pragma unroll
    for (int i = 0; i < DIM; ++i) {
        float v = ((i >> 3) & 1) ? si[0] : ci[0];
        v      *= ((i >> 2) & 1) ? si[1] : ci[1];
        v      *= ((i >> 1) & 1) ? si[2] : ci[2];
        v      *= ((i >> 0) & 1) ? si[3] : ci[3];
        re[i] = v;
        im[i] = 0.0f;
    }

#pragma unroll
    for (int l = 0; l < NL; ++l) {
        // RX(weights[l][q]) on each qubit: [[c, -is], [-is, c]]
#pragma unroll
        for (int q = 0; q < NQ; ++q) {
            float c = cw[l * NQ + q];
            float s = sw[l * NQ + q];
            const int tbit = 1 << (3 - q);
#pragma unroll
            for (int i = 0; i < DIM; ++i) {
                if (!(i & tbit)) {
                    const int j = i | tbit;
                    float r0 = re[i], i0 = im[i];
                    float r1 = re[j], i1 = im[j];
                    re[i] = c * r0 + s * i1;
                    im[i] = c * i0 - s * r1;
                    re[j] = c * r1 + s * i0;
                    im[j] = c * i1 - s * r0;
                }
            }
        }
        // CNOT ring: control q, target (q+1)%4, applied sequentially.
        // new[i] = old[i ^ tbit] when control bit of i is set (pure register perm).
#pragma unroll
        for (int q = 0; q < NQ; ++q) {
            const int cbit = 1 << (3 - q);
            const int tbit = 1 << (3 - ((q + 1) % NQ));
            float nr[DIM], ni[DIM];
#pragma unroll
            for (int i = 0; i < DIM; ++i) {
                const int j = (i & cbit) ? (i ^ tbit) : i;
                nr[i] = re[j];
                ni[i] = im[j];
            }
#pragma unroll
            for (int i = 0; i < DIM; ++i) {
                re[i] = nr[i];
                im[i] = ni[i];
            }
        }
    }

    // probs -> Z expectations per qubit.
    float p[DIM];
#pragma unroll
    for (int i = 0; i < DIM; ++i) p[i] = re[i] * re[i] + im[i] * im[i];

    float oq[NQ];
#pragma unroll
    for (int q = 0; q < NQ; ++q) {
        float acc = 0.0f;
#pragma unroll
        for (int i = 0; i < DIM; ++i) {
            acc = ((i >> (3 - q)) & 1) ? (acc - p[i]) : (acc + p[i]);
        }
        oq[q] = acc;
    }
    reinterpret_cast<float4*>(out)[b] = make_float4(oq[0], oq[1], oq[2], oq[3]);
}

extern "C" void kernel_launch(void* const* d_in, const int* in_sizes, int n_in,
                              void* d_out, int out_size, void* d_ws, size_t ws_size,
                              hipStream_t stream) {
    const float* inputs  = (const float*)d_in[0];
    const float* weights = (const float*)d_in[1];
    float* out = (float*)d_out;
    float* wcs = (float*)d_ws;

    const int B = in_sizes[0] / NQ;

    qlayer_prep<<<1, 64, 0, stream>>>(weights, wcs);
    qlayer_main<<<(B + 255) / 256, 256, 0, stream>>>(inputs, wcs, out, B);
}

// Round 2
// 81.746 us; speedup vs baseline: 1.0941x; 1.0941x over previous
//
#include <hip/hip_runtime.h>

#define NQ 4
#define DIM 16
#define NL 3
#define EPT 4          // batch elements per thread
#define BLK 256

__global__ __launch_bounds__(BLK) void qlayer_fused(const float* __restrict__ inputs,
                                                    const float* __restrict__ weights,
                                                    float* __restrict__ out, int B) {
    // Uniform weight trig, computed per-thread (cheaper than a serialized prep
    // kernel launch), amortized over EPT elements.
    float cw[NL * NQ], sw[NL * NQ];
#pragma unroll
    for (int i = 0; i < NL * NQ; ++i) {
        float t = 0.5f * weights[i];   // uniform -> scalar loads
        cw[i] = __cosf(t);
        sw[i] = __sinf(t);
    }

    const int base = blockIdx.x * (BLK * EPT) + threadIdx.x;

#pragma unroll
    for (int e = 0; e < EPT; ++e) {
        const int b = base + e * BLK;
        if (b >= B) continue;

        // Per-batch RY angles (vectorized 16B load).
        float4 in = reinterpret_cast<const float4*>(inputs)[b];
        float ci[NQ], si[NQ];
        {
            float a;
            a = 0.5f * in.x; ci[0] = __cosf(a); si[0] = __sinf(a);
            a = 0.5f * in.y; ci[1] = __cosf(a); si[1] = __sinf(a);
            a = 0.5f * in.z; ci[2] = __cosf(a); si[2] = __sinf(a);
            a = 0.5f * in.w; ci[3] = __cosf(a); si[3] = __sinf(a);
        }

        // Initial product state (all-real) via factor tree: 24 muls.
        // Qubit q corresponds to bit (3-q) of the state index (MSB-first).
        float f01[4], f23[4];
        f01[0] = ci[0] * ci[1]; f01[1] = ci[0] * si[1];
        f01[2] = si[0] * ci[1]; f01[3] = si[0] * si[1];
        f23[0] = ci[2] * ci[3]; f23[1] = ci[2] * si[3];
        f23[2] = si[2] * ci[3]; f23[3] = si[2] * si[3];

        float re[DIM], im[DIM];
#pragma unroll
        for (int i = 0; i < DIM; ++i) {
            re[i] = f01[i >> 2] * f23[i & 3];
            im[i] = 0.0f;
        }

#pragma unroll
        for (int l = 0; l < NL; ++l) {
            // RX(weights[l][q]) on qubit q: [[c, -is], [-is, c]]
#pragma unroll
            for (int q = 0; q < NQ; ++q) {
                const float c = cw[l * NQ + q];
                const float s = sw[l * NQ + q];
                const int tbit = 1 << (3 - q);
#pragma unroll
                for (int i = 0; i < DIM; ++i) {
                    if (!(i & tbit)) {
                        const int j = i | tbit;
                        float r0 = re[i], i0 = im[i];
                        float r1 = re[j], i1 = im[j];
                        re[i] = c * r0 + s * i1;
                        im[i] = c * i0 - s * r1;
                        re[j] = c * r1 + s * i0;
                        im[j] = c * i1 - s * r0;
                    }
                }
            }
            // CNOT ring (control q, target (q+1)%4): compile-time register perm.
#pragma unroll
            for (int q = 0; q < NQ; ++q) {
                const int cbit = 1 << (3 - q);
                const int tbit = 1 << (3 - ((q + 1) % NQ));
                float nr[DIM], ni[DIM];
#pragma unroll
                for (int i = 0; i < DIM; ++i) {
                    const int j = (i & cbit) ? (i ^ tbit) : i;
                    nr[i] = re[j];
                    ni[i] = im[j];
                }
#pragma unroll
                for (int i = 0; i < DIM; ++i) {
                    re[i] = nr[i];
                    im[i] = ni[i];
                }
            }
        }

        // probs
        float p[DIM];
#pragma unroll
        for (int i = 0; i < DIM; ++i) p[i] = re[i] * re[i] + im[i] * im[i];

        // Z expectations via partial-sum (Walsh) tree: ~40 ops instead of 64.
        float s1[8], z3 = 0.0f;
#pragma unroll
        for (int k = 0; k < 8; ++k) {
            s1[k] = p[2 * k] + p[2 * k + 1];
            z3 += p[2 * k] - p[2 * k + 1];
        }
        float s2[4], z2 = 0.0f;
#pragma unroll
        for (int k = 0; k < 4; ++k) {
            s2[k] = s1[2 * k] + s1[2 * k + 1];
            z2 += s1[2 * k] - s1[2 * k + 1];
        }
        float z1 = (s2[0] - s2[1]) + (s2[2] - s2[3]);
        float z0 = (s2[0] + s2[1]) - (s2[2] + s2[3]);

        reinterpret_cast<float4*>(out)[b] = make_float4(z0, z1, z2, z3);
    }
}

extern "C" void kernel_launch(void* const* d_in, const int* in_sizes, int n_in,
                              void* d_out, int out_size, void* d_ws, size_t ws_size,
                              hipStream_t stream) {
    const float* inputs  = (const float*)d_in[0];
    const float* weights = (const float*)d_in[1];
    float* out = (float*)d_out;

    const int B = in_sizes[0] / NQ;
    const int grid = (B + BLK * EPT - 1) / (BLK * EPT);

    qlayer_fused<<<grid, BLK, 0, stream>>>(inputs, weights, out, B);
}

// Round 3
// 79.339 us; speedup vs baseline: 1.1273x; 1.0303x over previous
//
#include <hip/hip_runtime.h>

#define NQ 4
#define DIM 16
#define NL 3
#define EPT 8
#define BLK 256

// In-place 16-point Walsh-Hadamard transform (unnormalized, symmetric):
// X[m] = sum_j (-1)^popcount(m&j) x[j]
#define WHT16(a)                                                        \
    do {                                                                \
        _Pragma("unroll")                                               \
        for (int _len = 1; _len < DIM; _len <<= 1) {                    \
            _Pragma("unroll")                                           \
            for (int _i = 0; _i < DIM; ++_i) {                          \
                if (!(_i & _len)) {                                     \
                    float _x = (a)[_i], _y = (a)[_i + _len];            \
                    (a)[_i] = _x + _y;                                  \
                    (a)[_i + _len] = _x - _y;                           \
                }                                                       \
            }                                                           \
        }                                                               \
    } while (0)

__global__ __launch_bounds__(BLK) void qlayer_walsh(const float* __restrict__ inputs,
                                                    const float* __restrict__ weights,
                                                    float* __restrict__ out, int B) {
    // ---- uniform (weights-only) work, amortized over EPT elements ----
    // The full weight circuit == P * exp(-i/2 * sum_k theta_k * Xstring_k),
    // P = 3 CNOT rings (folded into measurement masks). X-strings commute and
    // diagonalize under H^{x4}: circuit = P * W * diag(e^{-i Lambda}) * W / 16.
    // Lambda = WHT(T), T[mask_k] = theta_k / 2. String masks (index-bit space,
    // qubit q <-> bit 3-q), derived by conjugating X_q through the CNOT rings:
    //   layer0: 8,4,2,1   layer1: 12,6,3,13   layer2: 10,5,14,7
    float L[DIM];
#pragma unroll
    for (int i = 0; i < DIM; ++i) L[i] = 0.0f;
    L[8]  = 0.5f * weights[0];
    L[4]  = 0.5f * weights[1];
    L[2]  = 0.5f * weights[2];
    L[1]  = 0.5f * weights[3];
    L[12] = 0.5f * weights[4];
    L[6]  = 0.5f * weights[5];
    L[3]  = 0.5f * weights[6];
    L[13] = 0.5f * weights[7];
    L[10] = 0.5f * weights[8];
    L[5]  = 0.5f * weights[9];
    L[14] = 0.5f * weights[10];
    L[7]  = 0.5f * weights[11];
    WHT16(L);

    float cL[DIM], sL[DIM];
#pragma unroll
    for (int i = 0; i < DIM; ++i) {
        cL[i] = __cosf(L[i]);
        sL[i] = __sinf(L[i]);
    }

    const int base = blockIdx.x * (BLK * EPT) + threadIdx.x;

#pragma unroll
    for (int e = 0; e < EPT; ++e) {
        const int b = base + e * BLK;
        if (b >= B) continue;

        float4 in = reinterpret_cast<const float4*>(inputs)[b];

        // RY product state (c,s) per qubit, then per-qubit Hadamard:
        // u = c+s, v = c-s  (unnormalized; total 1/16 fixed at the end)
        float u[NQ], v[NQ];
        {
            float a, c, s;
            a = 0.5f * in.x; c = __cosf(a); s = __sinf(a); u[0] = c + s; v[0] = c - s;
            a = 0.5f * in.y; c = __cosf(a); s = __sinf(a); u[1] = c + s; v[1] = c - s;
            a = 0.5f * in.z; c = __cosf(a); s = __sinf(a); u[2] = c + s; v[2] = c - s;
            a = 0.5f * in.w; c = __cosf(a); s = __sinf(a); u[3] = c + s; v[3] = c - s;
        }

        // phi = W * psi : still a product state. bit(3-q) selects v_q.
        float f01[4], f23[4];
        f01[0] = u[0] * u[1]; f01[1] = u[0] * v[1];
        f01[2] = v[0] * u[1]; f01[3] = v[0] * v[1];
        f23[0] = u[2] * u[3]; f23[1] = u[2] * v[3];
        f23[2] = v[2] * u[3]; f23[3] = v[2] * v[3];

        // Apply diagonal phase e^{-i Lambda} then the second WHT.
        float re[DIM], im[DIM];
#pragma unroll
        for (int i = 0; i < DIM; ++i) {
            float g = f01[i >> 2] * f23[i & 3];
            re[i] = g * cL[i];
            im[i] = -g * sL[i];
        }
        WHT16(re);
        WHT16(im);

        // probs (unnormalized by 256)
        float p[DIM];
#pragma unroll
        for (int i = 0; i < DIM; ++i) p[i] = re[i] * re[i] + im[i] * im[i];

        // Z expectations: Walsh coefficients of p at the P-pulled-back masks
        // M = {4, 6, 3, 9} for qubits 0..3, scaled by 1/256.
        WHT16(p);
        const float inv = 1.0f / 256.0f;
        reinterpret_cast<float4*>(out)[b] =
            make_float4(p[4] * inv, p[6] * inv, p[3] * inv, p[9] * inv);
    }
}

extern "C" void kernel_launch(void* const* d_in, const int* in_sizes, int n_in,
                              void* d_out, int out_size, void* d_ws, size_t ws_size,
                              hipStream_t stream) {
    const float* inputs  = (const float*)d_in[0];
    const float* weights = (const float*)d_in[1];
    float* out = (float*)d_out;

    const int B = in_sizes[0] / NQ;
    const int grid = (B + BLK * EPT - 1) / (BLK * EPT);

    qlayer_walsh<<<grid, BLK, 0, stream>>>(inputs, weights, out, B);
}